// Round 3
// baseline (3348.773 us; speedup 1.0000x reference)
//
#include <hip/hip_runtime.h>

// ---------------------------------------------------------------------------
// GRU decoder w/ attention. Round 3: 4 dispatches/step + bf16 MFMA GEMMs.
// R2 post-mortem: f32 4x4 micro-kernel LDS-BW-bound + 5 gaps/step -> 93us/step.
// Now: full-K MFMA (no k-split partials), bf16 weights/activation shadows,
// attention kernel recombines out[b] per-block (512 GRU evals) + q GEMV.
// ---------------------------------------------------------------------------

typedef unsigned short u16;
using bf16x8 = __attribute__((ext_vector_type(8))) short;
using f32x4  = __attribute__((ext_vector_type(4))) float;

// ---- f32 workspace offsets ----
#define OFF_EGI    0           // [32][64][1536] emb part of gi0 (+b_ih0)
#define OFF_EREAD  3145728     // [32][64][512]  emb part of readout (+b_read)
#define OFF_ATTPRE 4194304     // [64*128][512]  attn precompute (+b_pre)
#define OFF_GI0    8388608     // [64][1536] (incl Egi)
#define OFF_GH0    8486912     // [64][1536] (incl b_hh0)
#define OFF_GH1    8585216     // [64][1536] (incl b_hh1)
#define OFF_GI1    8683520     // [64][1536] (incl b_ih1)
#define OFF_RO0    8781824     // [64][512] readout out-part
#define OFF_RO1    8814592     // [64][512] readout ctx-part
#define OFF_H0     8847360     // [2][64][512] f32
#define OFF_H1     8912896
#define OFF_CTX    8978432     // f32 region ends at 9043968 floats

// ---- u16 (bf16) offsets relative to (u16*)wsf ----
#define UB_WIH0C   18087936    // [1536][512]  W_ih0 ctx-half
#define UB_WHH0    18874368    // [1536][512]
#define UB_WHH1    19660800    // [1536][512]
#define UB_WIH1    20447232    // [1536][512]
#define UB_WRO     21233664    // [512][512]  W_read out-cols
#define UB_WRC     21495808    // [512][512]  W_read ctx-cols
#define UB_CTXT    21757952    // [64][128][512] ctx transposed bf16
#define UB_H0B     25952256    // [64][512]
#define UB_H1B     25985024
#define UB_CTXB    26017792    // ends 26050560 u16 = 52.1 MB

// ---- output layout (float offsets into d_out) ----
#define OO_G    0
#define OO_C    524288
#define OO_CP   786432
#define OO_HID  788480
#define OO_AL   854016
#define OO_CTXF 862208

__device__ __forceinline__ float sigm(float x) {
    return 1.0f / (1.0f + __expf(-x));
}
__device__ __forceinline__ float tanh_(float x) {
    x = fmaxf(x, -15.f);
    float e = __expf(-2.0f * x);
    return (1.0f - e) / (1.0f + e);
}
__device__ __forceinline__ float gru_out(float ir, float iz, float in_,
                                         float hr, float hz, float hn, float hp) {
    float r = sigm(ir + hr), z = sigm(iz + hz);
    float n = tanh_(in_ + r * hn);
    return (1.f - z) * n + z * hp;
}
__device__ __forceinline__ u16 f2b(float x) {
    unsigned u = __float_as_uint(x);
    return (u16)((u + 0x7FFFu + ((u >> 16) & 1u)) >> 16);
}
__device__ __forceinline__ float b2f(unsigned u) {
    return __uint_as_float(u << 16);
}

// ========== f32 tiled GEMM (upfront only) ==========
__device__ __forceinline__ void gemm64(
    const float* __restrict__ xrow, const float* __restrict__ wrow,
    int kt0, int nkt, float* lds_x, float* lds_w,
    float* __restrict__ outp, int JW, int orow0, int j0,
    const float* __restrict__ addp, int addmode, int addJW)
{
    const int tid = threadIdx.x;
    const int tb4 = tid >> 4, tj4 = tid & 15;
    float acc[4][4];
#pragma unroll
    for (int a = 0; a < 4; ++a)
#pragma unroll
        for (int b = 0; b < 4; ++b) acc[a][b] = 0.f;

    for (int kt = kt0; kt < kt0 + nkt; ++kt) {
        const int kb = kt << 6;
        __syncthreads();
        {
            const int rl = tid >> 2;
#pragma unroll
            for (int i = 0; i < 4; ++i) {
                const int kk = ((tid & 3) << 4) + (i << 2);
                float4 xv = *(const float4*)(xrow + kb + kk);
                float4 wv = *(const float4*)(wrow + kb + kk);
                lds_x[(kk + 0) * 64 + rl] = xv.x;
                lds_x[(kk + 1) * 64 + rl] = xv.y;
                lds_x[(kk + 2) * 64 + rl] = xv.z;
                lds_x[(kk + 3) * 64 + rl] = xv.w;
                lds_w[(kk + 0) * 64 + rl] = wv.x;
                lds_w[(kk + 1) * 64 + rl] = wv.y;
                lds_w[(kk + 2) * 64 + rl] = wv.z;
                lds_w[(kk + 3) * 64 + rl] = wv.w;
            }
        }
        __syncthreads();
#pragma unroll 4
        for (int kk = 0; kk < 64; ++kk) {
            float4 xv = *(const float4*)(lds_x + kk * 64 + tb4 * 4);
            float4 wv = *(const float4*)(lds_w + kk * 64 + tj4 * 4);
            acc[0][0] += xv.x * wv.x; acc[0][1] += xv.x * wv.y;
            acc[0][2] += xv.x * wv.z; acc[0][3] += xv.x * wv.w;
            acc[1][0] += xv.y * wv.x; acc[1][1] += xv.y * wv.y;
            acc[1][2] += xv.y * wv.z; acc[1][3] += xv.y * wv.w;
            acc[2][0] += xv.z * wv.x; acc[2][1] += xv.z * wv.y;
            acc[2][2] += xv.z * wv.z; acc[2][3] += xv.z * wv.w;
            acc[3][0] += xv.w * wv.x; acc[3][1] += xv.w * wv.y;
            acc[3][2] += xv.w * wv.z; acc[3][3] += xv.w * wv.w;
        }
    }
#pragma unroll
    for (int ib = 0; ib < 4; ++ib) {
        const int row = tb4 * 4 + ib;
        const int jc = j0 + tj4 * 4;
        float4 r;
        r.x = acc[ib][0]; r.y = acc[ib][1]; r.z = acc[ib][2]; r.w = acc[ib][3];
        if (addmode == 1) {
            float4 bv = *(const float4*)(addp + jc);
            r.x += bv.x; r.y += bv.y; r.z += bv.z; r.w += bv.w;
        } else if (addmode == 2) {
            float4 bv = *(const float4*)(addp + (size_t)(orow0 + row) * addJW + jc);
            r.x += bv.x; r.y += bv.y; r.z += bv.z; r.w += bv.w;
        }
        *(float4*)(outp + (size_t)(orow0 + row) * JW + jc) = r;
    }
}

// ========== bf16 MFMA GEMM: D[64x64] = X[64x512] @ W[64x512]^T ==========
// X staged in LDS (bf16, XOR-swizzled); W read directly from global bf16.
// wave w owns rows w*16..w*16+15; 4 col-blocks of 16.
__device__ __forceinline__ void stage_bf16(const u16* __restrict__ Xg, u16* sX) {
    const int tid = threadIdx.x;
#pragma unroll
    for (int p = 0; p < 16; ++p) {
        const int chunk = p * 256 + tid;          // 4096 chunks of 16B
        const int row = chunk >> 6, cb16 = chunk & 63;
        const int src = row * 1024 + cb16 * 16;   // bytes
        const int dst = row * 1024 + ((cb16 * 16) ^ ((row & 7) << 4));
        *(float4*)((char*)sX + dst) = *(const float4*)((const char*)Xg + src);
    }
}

// mode 0: store; 1: +addp[col]; 2: +addp[row*addJW+col].  (addp pre-offset by j0)
__device__ __forceinline__ void mfma_gemm64(const u16* sX, const u16* __restrict__ Wg,
        float* __restrict__ outp, int JW,
        const float* __restrict__ addp, int mode, int addJW)
{
    const int tid = threadIdx.x;
    const int w = tid >> 6, l = tid & 63;
    const int l15 = l & 15, lhi = l >> 4;
    f32x4 acc0 = {0.f,0.f,0.f,0.f}, acc1 = acc0, acc2 = acc0, acc3 = acc0;
    const int arow = w * 16 + l15;
    const char* aptr = (const char*)sX;
    const int abase = arow * 1024 + lhi * 16;
    const int aswz = (arow & 7) << 4;
#pragma unroll 4
    for (int ks = 0; ks < 16; ++ks) {
        bf16x8 a = *(const bf16x8*)(aptr + ((abase + ks * 64) ^ aswz));
        const u16* wp = Wg + l15 * 512 + ks * 32 + lhi * 8;
        bf16x8 b0 = *(const bf16x8*)(wp);
        bf16x8 b1 = *(const bf16x8*)(wp + 16 * 512);
        bf16x8 b2 = *(const bf16x8*)(wp + 32 * 512);
        bf16x8 b3 = *(const bf16x8*)(wp + 48 * 512);
        acc0 = __builtin_amdgcn_mfma_f32_16x16x32_bf16(a, b0, acc0, 0, 0, 0);
        acc1 = __builtin_amdgcn_mfma_f32_16x16x32_bf16(a, b1, acc1, 0, 0, 0);
        acc2 = __builtin_amdgcn_mfma_f32_16x16x32_bf16(a, b2, acc2, 0, 0, 0);
        acc3 = __builtin_amdgcn_mfma_f32_16x16x32_bf16(a, b3, acc3, 0, 0, 0);
    }
    f32x4 accs[4] = {acc0, acc1, acc2, acc3};
#pragma unroll
    for (int cb = 0; cb < 4; ++cb) {
        const int col = cb * 16 + l15;
#pragma unroll
        for (int r = 0; r < 4; ++r) {
            const int row = w * 16 + lhi * 4 + r;
            float v = accs[cb][r];
            if (mode == 1) v += addp[col];
            else if (mode == 2) v += addp[row * addJW + col];
            outp[(size_t)row * JW + col] = v;
        }
    }
}

// =================== upfront ===================
__global__ __launch_bounds__(256)
void k_upfront(const int* __restrict__ inp, const float* __restrict__ hid,
               const float* __restrict__ ctxin, const float* __restrict__ init_att,
               const float* __restrict__ embW,
               const float* __restrict__ W_ih0, const float* __restrict__ b_ih0,
               const float* __restrict__ W_hh0, const float* __restrict__ W_hh1,
               const float* __restrict__ W_ih1,
               const float* __restrict__ W_read, const float* __restrict__ b_read,
               const float* __restrict__ W_pre, const float* __restrict__ b_pre,
               float* __restrict__ wsf)
{
    __shared__ float lds_x[4096], lds_w[4096];
    u16* wsu = (u16*)wsf;
    const int jid = blockIdx.x, tid = threadIdx.x, rl = tid >> 2;
    if (jid < 768) {
        const int mt = jid / 24, jt = jid % 24, j0 = jt << 6;
        const int idx = inp[mt * 64 + rl];
        gemm64(embW + (size_t)idx * 512, W_ih0 + (size_t)(j0 + rl) * 1024,
               0, 8, lds_x, lds_w, wsf + OFF_EGI, 1536, mt << 6, j0, b_ih0, 1, 0);
    } else if (jid < 1024) {
        const int r = jid - 768, mt = r >> 3, jt = r & 7, j0 = jt << 6;
        const int idx = inp[mt * 64 + rl];
        gemm64(embW + (size_t)idx * 512, W_read + (size_t)(j0 + rl) * 1536,
               0, 8, lds_x, lds_w, wsf + OFF_EREAD, 512, mt << 6, j0, b_read, 1, 0);
    } else if (jid < 2048) {
        const int r = jid - 1024, mt = r >> 3, jt = r & 7, j0 = jt << 6;
        const int m = (mt << 6) + rl, b = m >> 7, s = m & 127;
        gemm64(ctxin + (size_t)((s << 6) + b) * 512, W_pre + (size_t)(j0 + rl) * 512,
               0, 8, lds_x, lds_w, wsf + OFF_ATTPRE, 512, mt << 6, j0, b_pre, 1, 0);
    } else if (jid < 2054) {
        // f32 state init at index 1 (t=0 has prv=1)
        const int job = jid - 2048, buf = job >> 1, half = job & 1;
        const float* src = buf == 0 ? hid : (buf == 1 ? hid + 32768 : init_att);
        float* dst = wsf + (buf == 0 ? OFF_H0 : (buf == 1 ? OFF_H1 : OFF_CTX)) + 32768;
        for (int i = 0; i < 64; ++i) {
            int e = half * 16384 + i * 256 + tid;
            dst[e] = src[e];
        }
    } else if (jid < 2278) {
        // weight conversions to bf16
        const int w = jid - 2054;
        if (w < 48) {
            for (int i = 0; i < 64; ++i) {
                int e = w * 16384 + i * 256 + tid;
                int j = e >> 9, k = e & 511;
                wsu[UB_WIH0C + e] = f2b(W_ih0[(size_t)j * 1024 + 512 + k]);
            }
        } else if (w < 96) {
            for (int i = 0; i < 64; ++i) {
                int e = (w - 48) * 16384 + i * 256 + tid;
                wsu[UB_WHH0 + e] = f2b(W_hh0[e]);
            }
        } else if (w < 144) {
            for (int i = 0; i < 64; ++i) {
                int e = (w - 96) * 16384 + i * 256 + tid;
                wsu[UB_WHH1 + e] = f2b(W_hh1[e]);
            }
        } else if (w < 192) {
            for (int i = 0; i < 64; ++i) {
                int e = (w - 144) * 16384 + i * 256 + tid;
                wsu[UB_WIH1 + e] = f2b(W_ih1[e]);
            }
        } else if (w < 208) {
            for (int i = 0; i < 64; ++i) {
                int e = (w - 192) * 16384 + i * 256 + tid;
                int j = e >> 9, k = e & 511;
                wsu[UB_WRO + e] = f2b(W_read[(size_t)j * 1536 + 512 + k]);
            }
        } else {
            for (int i = 0; i < 64; ++i) {
                int e = (w - 208) * 16384 + i * 256 + tid;
                int j = e >> 9, k = e & 511;
                wsu[UB_WRC + e] = f2b(W_read[(size_t)j * 1536 + 1024 + k]);
            }
        }
    } else if (jid < 2534) {
        // ctxT bf16 [b][s][e]
        const int w2 = jid - 2278;
        for (int rr = 0; rr < 32; ++rr) {
            const int r = w2 * 32 + rr;
            const int b = r >> 7, s = r & 127;
            const float* src = ctxin + ((size_t)s * 64 + b) * 512;
#pragma unroll
            for (int h = 0; h < 2; ++h) {
                int e = h * 256 + tid;
                wsu[UB_CTXT + (size_t)r * 512 + e] = f2b(src[e]);
            }
        }
    } else {
        const int job = jid - 2534;
        const float* src = job == 0 ? hid : (job == 1 ? hid + 32768 : init_att);
        u16* dst = wsu + (job == 0 ? UB_H0B : (job == 1 ? UB_H1B : UB_CTXB));
        for (int i = 0; i < 128; ++i) {
            int e = i * 256 + tid;
            dst[e] = f2b(src[e]);
        }
    }
}

// =================== A: gate GEMMs + readout(t-1), 88 blocks ===============
__global__ __launch_bounds__(256)
void k_pA(int t, const float* __restrict__ b_hh0, const float* __restrict__ b_hh1,
          float* __restrict__ wsf)
{
    __shared__ u16 sX[64 * 512];
    u16* wsu = (u16*)wsf;
    const int blk = blockIdx.x;
    if (blk < 24) {
        stage_bf16(wsu + UB_CTXB, sX);
        __syncthreads();
        const int jt = blk, j0 = jt << 6;
        mfma_gemm64(sX, wsu + UB_WIH0C + jt * 32768, wsf + OFF_GI0 + j0, 1536,
                    wsf + OFF_EGI + (size_t)t * 98304 + j0, 2, 1536);
    } else if (blk < 48) {
        stage_bf16(wsu + UB_H0B, sX);
        __syncthreads();
        const int jt = blk - 24, j0 = jt << 6;
        mfma_gemm64(sX, wsu + UB_WHH0 + jt * 32768, wsf + OFF_GH0 + j0, 1536,
                    b_hh0 + j0, 1, 0);
    } else if (blk < 72) {
        stage_bf16(wsu + UB_H1B, sX);
        __syncthreads();
        const int jt = blk - 48, j0 = jt << 6;
        mfma_gemm64(sX, wsu + UB_WHH1 + jt * 32768, wsf + OFF_GH1 + j0, 1536,
                    b_hh1 + j0, 1, 0);
    } else if (blk < 80) {
        if (t == 0) return;
        stage_bf16(wsu + UB_H1B, sX);
        __syncthreads();
        const int jt = blk - 72, j0 = jt << 6;
        mfma_gemm64(sX, wsu + UB_WRO + jt * 32768, wsf + OFF_RO0 + j0, 512,
                    nullptr, 0, 0);
    } else {
        if (t == 0) return;
        stage_bf16(wsu + UB_CTXB, sX);
        __syncthreads();
        const int jt = blk - 80, j0 = jt << 6;
        mfma_gemm64(sX, wsu + UB_WRC + jt * 32768, wsf + OFF_RO1 + j0, 512,
                    nullptr, 0, 0);
    }
}

// =================== B: h0 combine (16) + maxout(t-1) (8), 24 blocks =======
__global__ __launch_bounds__(256)
void k_pB(int t, float* __restrict__ wsf, float* __restrict__ dout)
{
    u16* wsu = (u16*)wsf;
    const int blk = blockIdx.x, tid = threadIdx.x;
    const int cur = t & 1, prv = cur ^ 1;
    if (blk < 16) {
        float* h0_cur = wsf + OFF_H0 + cur * 32768;
        const float* h0_prv = wsf + OFF_H0 + prv * 32768;
        const float* GIp = wsf + OFF_GI0;
        const float* GHp = wsf + OFF_GH0;
        u16* h0b = wsu + UB_H0B;
#pragma unroll
        for (int i = 0; i < 8; ++i) {
            const int e = (blk << 11) + (i << 8) + tid;
            const int b = e >> 9, c = e & 511;
            const int base = b * 1536 + c;
            float v = gru_out(GIp[base], GIp[base + 512], GIp[base + 1024],
                              GHp[base], GHp[base + 512], GHp[base + 1024],
                              h0_prv[b * 512 + c]);
            h0_cur[b * 512 + c] = v;
            h0b[b * 512 + c] = f2b(v);
        }
    } else {
        if (t == 0) return;
        const int r = blk - 16;
        const float* ERp = wsf + OFF_EREAD + (size_t)(t - 1) * 32768;
        const float* R0 = wsf + OFF_RO0;
        const float* R1 = wsf + OFF_RO1;
#pragma unroll
        for (int i = 0; i < 8; ++i) {
            const int e = (r << 11) + (i << 8) + tid;
            const int b = e >> 8, j2 = e & 255;
            const int bi = b * 512 + (j2 << 1);
            float v0 = ERp[bi]     + R0[bi]     + R1[bi];
            float v1 = ERp[bi + 1] + R0[bi + 1] + R1[bi + 1];
            dout[OO_G + (size_t)(t - 1) * 16384 + b * 256 + j2] = fmaxf(v0, v1);
        }
    }
}

// =================== C: gi1 MFMA, 24 blocks ===================
__global__ __launch_bounds__(256)
void k_pC(const float* __restrict__ b_ih1, float* __restrict__ wsf)
{
    __shared__ u16 sX[64 * 512];
    u16* wsu = (u16*)wsf;
    stage_bf16(wsu + UB_H0B, sX);
    __syncthreads();
    const int jt = blockIdx.x, j0 = jt << 6;
    mfma_gemm64(sX, wsu + UB_WIH1 + jt * 32768, wsf + OFF_GI1 + j0, 1536,
                b_ih1 + j0, 1, 0);
}

// =================== D: per-b attention, 64 blocks ===================
// out[b] recombine -> h1 + q GEMV -> energy -> softmax -> ctx -> copy gate
__global__ __launch_bounds__(256)
void k_pD(int t, const float* __restrict__ maskp, const float* __restrict__ w_v,
          const float* __restrict__ W_q, const float* __restrict__ W_copy,
          const float* __restrict__ b_copy, float* __restrict__ wsf,
          float* __restrict__ dout)
{
    __shared__ float s_out[512];
    __shared__ float s_q[512];
    __shared__ float s_e[128];
    __shared__ float s_at[128];
    __shared__ float s_ctx[512];
    __shared__ float s_red[256];
    u16* wsu = (u16*)wsf;
    const int b = blockIdx.x, tid = threadIdx.x;
    const int cur = t & 1, prv = cur ^ 1;

    // ---- recombine out[b] (layer-1 GRU output) ----
    {
        const float* GI1p = wsf + OFF_GI1 + b * 1536;
        const float* GH1p = wsf + OFF_GH1 + b * 1536;
        const float* h1p = wsf + OFF_H1 + prv * 32768 + b * 512;
        float* h1c = wsf + OFF_H1 + cur * 32768 + b * 512;
        u16* h1b = wsu + UB_H1B + b * 512;
        const int c0 = tid * 2;
        float2 gi_r = *(const float2*)(GI1p + c0);
        float2 gi_z = *(const float2*)(GI1p + 512 + c0);
        float2 gi_n = *(const float2*)(GI1p + 1024 + c0);
        float2 gh_r = *(const float2*)(GH1p + c0);
        float2 gh_z = *(const float2*)(GH1p + 512 + c0);
        float2 gh_n = *(const float2*)(GH1p + 1024 + c0);
        float2 hp = *(const float2*)(h1p + c0);
        float o0 = gru_out(gi_r.x, gi_z.x, gi_n.x, gh_r.x, gh_z.x, gh_n.x, hp.x);
        float o1 = gru_out(gi_r.y, gi_z.y, gi_n.y, gh_r.y, gh_z.y, gh_n.y, hp.y);
        s_out[c0] = o0; s_out[c0 + 1] = o1;
        *(float2*)(h1c + c0) = make_float2(o0, o1);
        *(unsigned*)(h1b + c0) = (unsigned)f2b(o0) | ((unsigned)f2b(o1) << 16);
    }
    __syncthreads();

    // ---- q[b] = out @ W_q^T (f32 GEMV) ----
    {
        float q0 = 0.f, q1 = 0.f;
        const float* w0 = W_q + (size_t)tid * 512;
        const float* w1 = W_q + (size_t)(tid + 256) * 512;
#pragma unroll 8
        for (int c = 0; c < 512; c += 4) {
            float4 ov = *(const float4*)(s_out + c);
            float4 a0 = *(const float4*)(w0 + c);
            float4 a1 = *(const float4*)(w1 + c);
            q0 += ov.x * a0.x + ov.y * a0.y + ov.z * a0.z + ov.w * a0.w;
            q1 += ov.x * a1.x + ov.y * a1.y + ov.z * a1.z + ov.w * a1.w;
        }
        s_q[tid] = q0; s_q[tid + 256] = q1;
    }
    __syncthreads();

    // ---- energy[s] = w_v . tanh(pre[b,s,:] + q) ----
    {
        const int wid = tid >> 6, lane = tid & 63;
        for (int s = wid; s < 128; s += 4) {
            const float* pre = wsf + OFF_ATTPRE + ((size_t)b * 128 + s) * 512;
            float acc = 0.f;
#pragma unroll
            for (int i = 0; i < 8; ++i) {
                const int a = lane + (i << 6);
                acc += tanh_(pre[a] + s_q[a]) * w_v[a];
            }
#pragma unroll
            for (int d2 = 1; d2 < 64; d2 <<= 1) acc += __shfl_xor(acc, d2, 64);
            if (lane == 0)
                s_e[s] = (maskp[b * 128 + s] > 0.5f) ? -3.0e38f : acc;
        }
    }
    __syncthreads();

    // ---- softmax over S=128 ----
    if (tid < 64) {
        float e0 = s_e[tid], e1 = s_e[tid + 64];
        float mx = fmaxf(e0, e1);
#pragma unroll
        for (int d2 = 1; d2 < 64; d2 <<= 1) mx = fmaxf(mx, __shfl_xor(mx, d2, 64));
        float x0 = __expf(e0 - mx), x1 = __expf(e1 - mx);
        float sm = x0 + x1;
#pragma unroll
        for (int d2 = 1; d2 < 64; d2 <<= 1) sm += __shfl_xor(sm, d2, 64);
        float inv = 1.f / sm;
        x0 *= inv; x1 *= inv;
        s_at[tid] = x0; s_at[tid + 64] = x1;
        float* co = dout + OO_C + ((size_t)t * 64 + b) * 128;
        co[tid] = x0; co[tid + 64] = x1;
        if (t == 31) {
            dout[OO_AL + b * 128 + tid] = x0;
            dout[OO_AL + b * 128 + tid + 64] = x1;
        }
    }
    __syncthreads();

    // ---- new_ctx = attn @ ctx (ctxT bf16 [b][s][512]) ----
    {
        const int e0 = tid * 2;
        const u16* ct = wsu + UB_CTXT + (size_t)b * 65536 + e0;
        float a0 = 0.f, a1 = 0.f;
#pragma unroll 4
        for (int s = 0; s < 128; ++s) {
            float at = s_at[s];
            unsigned pv = *(const unsigned*)(ct + s * 512);
            a0 = fmaf(at, b2f(pv & 0xffffu), a0);
            a1 = fmaf(at, b2f(pv >> 16), a1);
        }
        s_ctx[e0] = a0; s_ctx[e0 + 1] = a1;
        float* cc = wsf + OFF_CTX + cur * 32768 + b * 512;
        *(float2*)(cc + e0) = make_float2(a0, a1);
        *(unsigned*)(wsu + UB_CTXB + b * 512 + e0) =
            (unsigned)f2b(a0) | ((unsigned)f2b(a1) << 16);
    }
    __syncthreads();

    // ---- copy gate ----
    {
        float part = 0.f;
        for (int i2 = tid; i2 < 512; i2 += 256)
            part += s_out[i2] * W_copy[i2] + s_ctx[i2] * W_copy[512 + i2];
        s_red[tid] = part;
        __syncthreads();
        for (int d2 = 128; d2 > 0; d2 >>= 1) {
            if (tid < d2) s_red[tid] += s_red[tid + d2];
            __syncthreads();
        }
        if (tid == 0)
            dout[OO_CP + t * 64 + b] = sigm(s_red[0] + b_copy[0]);
    }
}

// =================== epilogue ===================
__global__ __launch_bounds__(256)
void k_roF(float* __restrict__ wsf, float* __restrict__ dout)
{
    __shared__ u16 sX[64 * 512];
    u16* wsu = (u16*)wsf;
    const int blk = blockIdx.x, tid = threadIdx.x;
    if (blk < 8) {
        stage_bf16(wsu + UB_H1B, sX);
        __syncthreads();
        const int j0 = blk << 6;
        mfma_gemm64(sX, wsu + UB_WRO + blk * 32768, wsf + OFF_RO0 + j0, 512,
                    nullptr, 0, 0);
    } else if (blk < 16) {
        stage_bf16(wsu + UB_CTXB, sX);
        __syncthreads();
        const int jt = blk - 8, j0 = jt << 6;
        mfma_gemm64(sX, wsu + UB_WRC + jt * 32768, wsf + OFF_RO1 + j0, 512,
                    nullptr, 0, 0);
    } else {
        const int job = blk - 16, buf = job >> 1, half = job & 1;
        const float* src = wsf + (buf == 0 ? OFF_H0 : (buf == 1 ? OFF_H1 : OFF_CTX)) + 32768;
        float* dst = dout + (buf == 0 ? OO_HID : (buf == 1 ? OO_HID + 32768 : OO_CTXF));
        for (int i = 0; i < 64; ++i) {
            int e = half * 16384 + i * 256 + tid;
            dst[e] = src[e];
        }
    }
}

__global__ __launch_bounds__(256)
void k_fin(float* __restrict__ wsf, float* __restrict__ dout)
{
    const int blk = blockIdx.x, tid = threadIdx.x;
    const float* ERp = wsf + OFF_EREAD + (size_t)31 * 32768;
    const float* R0 = wsf + OFF_RO0;
    const float* R1 = wsf + OFF_RO1;
#pragma unroll
    for (int i = 0; i < 8; ++i) {
        const int e = (blk << 11) + (i << 8) + tid;
        const int b = e >> 8, j2 = e & 255;
        const int bi = b * 512 + (j2 << 1);
        float v0 = ERp[bi]     + R0[bi]     + R1[bi];
        float v1 = ERp[bi + 1] + R0[bi + 1] + R1[bi + 1];
        dout[OO_G + (size_t)31 * 16384 + b * 256 + j2] = fmaxf(v0, v1);
    }
}

extern "C" void kernel_launch(void* const* d_in, const int* in_sizes, int n_in,
                              void* d_out, int out_size, void* d_ws, size_t ws_size,
                              hipStream_t stream) {
    const int*   inp      = (const int*)d_in[0];
    const float* hid      = (const float*)d_in[1];
    const float* ctxin    = (const float*)d_in[2];
    const float* maskp    = (const float*)d_in[3];
    const float* init_att = (const float*)d_in[4];
    const float* embW     = (const float*)d_in[5];
    const float* W_ih0    = (const float*)d_in[6];
    const float* b_ih0    = (const float*)d_in[7];
    const float* W_hh0    = (const float*)d_in[8];
    const float* b_hh0    = (const float*)d_in[9];
    const float* W_ih1    = (const float*)d_in[10];
    const float* b_ih1    = (const float*)d_in[11];
    const float* W_hh1    = (const float*)d_in[12];
    const float* b_hh1    = (const float*)d_in[13];
    const float* W_pre    = (const float*)d_in[14];
    const float* b_pre    = (const float*)d_in[15];
    const float* W_q      = (const float*)d_in[16];
    const float* w_v      = (const float*)d_in[17];
    const float* W_copy   = (const float*)d_in[18];
    const float* b_copy   = (const float*)d_in[19];
    const float* W_read   = (const float*)d_in[20];
    const float* b_read   = (const float*)d_in[21];
    float* dout = (float*)d_out;
    float* wsf  = (float*)d_ws;

    k_upfront<<<dim3(2537), dim3(256), 0, stream>>>(
        inp, hid, ctxin, init_att, embW, W_ih0, b_ih0, W_hh0, W_hh1, W_ih1,
        W_read, b_read, W_pre, b_pre, wsf);

    for (int t = 0; t < 32; ++t) {
        k_pA<<<dim3(88), dim3(256), 0, stream>>>(t, b_hh0, b_hh1, wsf);
        k_pB<<<dim3(24), dim3(256), 0, stream>>>(t, wsf, dout);
        k_pC<<<dim3(24), dim3(256), 0, stream>>>(b_ih1, wsf);
        k_pD<<<dim3(64), dim3(256), 0, stream>>>(t, maskp, w_v, W_q, W_copy,
                                                 b_copy, wsf, dout);
    }
    k_roF<<<dim3(22), dim3(256), 0, stream>>>(wsf, dout);
    k_fin<<<dim3(8), dim3(256), 0, stream>>>(wsf, dout);
}